// Round 10
// baseline (475.628 us; speedup 1.0000x reference)
//
#include <hip/hip_runtime.h>

#define M_NODES 100000
#define N_EDGES_C 800000
#define IN_DIM_C 128
#define HID_C 256
#define N_GRAPHS_C 256
#define BN_EPS_C 1e-5f

typedef __attribute__((ext_vector_type(8))) short short8v;
typedef __attribute__((ext_vector_type(4))) float floatx4;

__device__ __forceinline__ unsigned short bf16_rne(float f) {
    union { float f; unsigned u; } x; x.f = f;
    unsigned r = x.u + 0x7FFF + ((x.u >> 16) & 1);
    return (unsigned short)(r >> 16);
}
__device__ __forceinline__ float bf16_to_f(unsigned short h) {
    union { unsigned u; float f; } x; x.u = ((unsigned)h) << 16;
    return x.f;
}
__device__ __forceinline__ float bf16lo_f(unsigned u) {
    union { unsigned u; float f; } x; x.u = u << 16;
    return x.f;
}
__device__ __forceinline__ float bf16hi_f(unsigned u) {
    union { unsigned u; float f; } x; x.u = u & 0xffff0000u;
    return x.f;
}

// fragment-major W offset
template <int K>
__device__ __forceinline__ long long woff(int c, int k) {
    return ((long long)((k >> 5) * 16 + (c >> 4))) * 512 + ((k >> 3) & 3) * 128 +
           (c & 15) * 8 + (k & 7);
}

// ---------------- small helpers ----------------
__global__ void zero_f(float* __restrict__ p, int n) {
    int i = blockIdx.x * blockDim.x + threadIdx.x;
    if (i < n) p[i] = 0.f;
}
__global__ void zero_i(int* __restrict__ p, int n) {
    int i = blockIdx.x * blockDim.x + threadIdx.x;
    if (i < n) p[i] = 0;
}
__global__ void copy_i(const int* __restrict__ s, int* __restrict__ d, int n) {
    int i = blockIdx.x * blockDim.x + threadIdx.x;
    if (i < n) d[i] = s[i];
}
__global__ void f2b(const float4* __restrict__ in, ushort4* __restrict__ out, int n4) {
    int i = blockIdx.x * blockDim.x + threadIdx.x;
    if (i >= n4) return;
    float4 v = in[i];
    ushort4 o;
    o.x = bf16_rne(v.x); o.y = bf16_rne(v.y); o.z = bf16_rne(v.z); o.w = bf16_rne(v.w);
    out[i] = o;
}

// ---------------- W split -> fragment-major hi/lo planes ----------------
template <int K>
__global__ void wsplit(const float* __restrict__ W, unsigned short* __restrict__ hi,
                       unsigned short* __restrict__ lo) {
    int t = blockIdx.x * blockDim.x + threadIdx.x;
    if (t >= K * HID_C) return;
    int k = t % K, c = t / K;
    float w = W[(long long)k * HID_C + c];
    unsigned short h = bf16_rne(w);
    unsigned short l = bf16_rne(w - bf16_to_f(h));
    long long o = woff<K>(c, k);
    hi[o] = h;
    lo[o] = l;
}

// ---------------- CSR build ----------------
__global__ void csr_count(const int* __restrict__ dst, int* __restrict__ counts) {
    int e = blockIdx.x * blockDim.x + threadIdx.x;
    if (e < N_EDGES_C) atomicAdd(&counts[dst[e]], 1);
}

__global__ __launch_bounds__(256) void block_scan(const int* __restrict__ counts,
                                                  int* __restrict__ excl,
                                                  int* __restrict__ partials) {
    __shared__ int sm[256];
    int i = blockIdx.x * 256 + threadIdx.x;
    int v = (i < M_NODES) ? counts[i] : 0;
    sm[threadIdx.x] = v;
    __syncthreads();
    for (int off = 1; off < 256; off <<= 1) {
        int add = (threadIdx.x >= off) ? sm[threadIdx.x - off] : 0;
        __syncthreads();
        sm[threadIdx.x] += add;
        __syncthreads();
    }
    if (i <= M_NODES) excl[i] = sm[threadIdx.x] - v;
    if (threadIdx.x == 255) partials[blockIdx.x] = sm[255];
}

__global__ __launch_bounds__(512) void scan_partials(int* __restrict__ partials, int nb) {
    __shared__ int sm[512];
    int t = threadIdx.x;
    int v = (t < nb) ? partials[t] : 0;
    sm[t] = v;
    __syncthreads();
    for (int off = 1; off < 512; off <<= 1) {
        int add = (t >= off) ? sm[t - off] : 0;
        __syncthreads();
        sm[t] += add;
        __syncthreads();
    }
    if (t < nb) partials[t] = sm[t] - v;
}

__global__ void add_offsets(int* __restrict__ rowptr, const int* __restrict__ partials) {
    int i = blockIdx.x * 256 + threadIdx.x;
    if (i <= M_NODES) rowptr[i] += partials[blockIdx.x];
}

__global__ void csr_fill(const int* __restrict__ src, const int* __restrict__ dst,
                         int* __restrict__ fillpos, int* __restrict__ csr_src) {
    int e = blockIdx.x * blockDim.x + threadIdx.x;
    if (e >= N_EDGES_C) return;
    int pos = atomicAdd(&fillpos[dst[e]], 1);
    csr_src[pos] = src[e];
}

// ---------------- gather (bf16 normal-layout in) -> fragment-major bf16 A ----------------
template <int K, bool BN>
__global__ __launch_bounds__(256) void gather_frag(const unsigned short* __restrict__ h,
                                                   const int* __restrict__ rowptr,
                                                   const int* __restrict__ csr_src,
                                                   const float* __restrict__ ss,
                                                   unsigned short* __restrict__ outA) {
    constexpr int CH = K / 128;
    const int nlow = threadIdx.x & 15;
    const int q = threadIdx.x >> 4;
    const int node = blockIdx.x * 16 + nlow;
    if (node >= M_NODES) return;

    float a[CH][8];
    float sc[CH][8], sh[CH][8];
    if (BN) {
#pragma unroll
        for (int cc = 0; cc < CH; ++cc)
#pragma unroll
            for (int i = 0; i < 8; ++i) {
                int f = cc * 128 + q * 8 + i;
                sc[cc][i] = ss[f];
                sh[cc][i] = ss[HID_C + f];
            }
    }
#pragma unroll
    for (int cc = 0; cc < CH; ++cc) {
        uint4 u = *(const uint4*)(h + (long long)node * K + cc * 128 + q * 8);
        float t[8] = {bf16lo_f(u.x), bf16hi_f(u.x), bf16lo_f(u.y), bf16hi_f(u.y),
                      bf16lo_f(u.z), bf16hi_f(u.z), bf16lo_f(u.w), bf16hi_f(u.w)};
#pragma unroll
        for (int i = 0; i < 8; ++i)
            a[cc][i] = BN ? fmaxf(fmaf(t[i], sc[cc][i], sh[cc][i]), 0.f) : t[i];
    }
    int beg = rowptr[node], end = rowptr[node + 1];
    for (int e = beg; e < end; ++e) {
        long long s = csr_src[e];
#pragma unroll
        for (int cc = 0; cc < CH; ++cc) {
            uint4 u = *(const uint4*)(h + s * K + cc * 128 + q * 8);
            float t[8] = {bf16lo_f(u.x), bf16hi_f(u.x), bf16lo_f(u.y), bf16hi_f(u.y),
                          bf16lo_f(u.z), bf16hi_f(u.z), bf16lo_f(u.w), bf16hi_f(u.w)};
#pragma unroll
            for (int i = 0; i < 8; ++i)
                a[cc][i] += BN ? fmaxf(fmaf(t[i], sc[cc][i], sh[cc][i]), 0.f) : t[i];
        }
    }
#pragma unroll
    for (int cc = 0; cc < CH; ++cc) {
        uint4 o;
        o.x = (unsigned)bf16_rne(a[cc][0]) | ((unsigned)bf16_rne(a[cc][1]) << 16);
        o.y = (unsigned)bf16_rne(a[cc][2]) | ((unsigned)bf16_rne(a[cc][3]) << 16);
        o.z = (unsigned)bf16_rne(a[cc][4]) | ((unsigned)bf16_rne(a[cc][5]) << 16);
        o.w = (unsigned)bf16_rne(a[cc][6]) | ((unsigned)bf16_rne(a[cc][7]) << 16);
        long long off = ((long long)(node >> 4) * (K / 8) + cc * 16 + q) * 128 + nlow * 8;
        *(uint4*)(outA + off) = o;
    }
}

// ---------------- fused MLP, fragment-major, register double-buffered k-loop ----------------
#define S1_LOAD(AF, BH, BL, K0)                                                          \
    {                                                                                    \
        _Pragma("unroll") for (int i = 0; i < 4; ++i)                                    \
            AF[i] = *(const short8v*)(A + aseg[i] + (long long)(K0) * 16 + laneoff);     \
        _Pragma("unroll") for (int j = 0; j < 4; ++j) {                                  \
            long long wb = (long long)((K0) >> 5) * 8192 + (wquarter + j) * 512 + laneoff; \
            BH[j] = *(const short8v*)(W1h + wb);                                         \
            BL[j] = *(const short8v*)(W1l + wb);                                         \
        }                                                                                \
    }

#define S2_LOAD(AF, BH, BL, K0)                                                          \
    {                                                                                    \
        _Pragma("unroll") for (int i = 0; i < 4; ++i) {                                  \
            int row = i * 16 + l15;                                                      \
            int bo = (row * 512 + ((K0) + kgrp * 8) * 2) ^ ((row & 7) << 4);             \
            AF[i] = *(const short8v*)(lds_raw + bo);                                     \
        }                                                                                \
        _Pragma("unroll") for (int j = 0; j < 4; ++j) {                                  \
            long long wb = (long long)((K0) >> 5) * 8192 + (wquarter + j) * 512 + laneoff; \
            BH[j] = *(const short8v*)(W2h + wb);                                         \
            BL[j] = *(const short8v*)(W2l + wb);                                         \
        }                                                                                \
    }

#define DO_MFMA(AF, BH, BL)                                                              \
    {                                                                                    \
        __builtin_amdgcn_s_setprio(1);                                                   \
        _Pragma("unroll") for (int i = 0; i < 4; ++i)                                    \
            _Pragma("unroll") for (int j = 0; j < 4; ++j) {                              \
            acc[i][j] = __builtin_amdgcn_mfma_f32_16x16x32_bf16(AF[i], BH[j], acc[i][j], 0, 0, 0); \
            acc[i][j] = __builtin_amdgcn_mfma_f32_16x16x32_bf16(AF[i], BL[j], acc[i][j], 0, 0, 0); \
        }                                                                                \
        __builtin_amdgcn_s_setprio(0);                                                   \
    }

template <int K>
__global__ __launch_bounds__(256, 3) void fused_mlp(const unsigned short* __restrict__ A,
                                                    const unsigned short* __restrict__ W1h,
                                                    const unsigned short* __restrict__ W1l,
                                                    const float* __restrict__ b1,
                                                    const unsigned short* __restrict__ W2h,
                                                    const unsigned short* __restrict__ W2l,
                                                    const float* __restrict__ b2,
                                                    unsigned short* __restrict__ outH,
                                                    int M, float* __restrict__ bnsums) {
    __shared__ char lds_raw[32768];  // H tile: 64 rows x 256 cols bf16, XOR-swizzled

    const int tid = threadIdx.x;
    const int lane = tid & 63;
    const int wc = tid >> 6;
    const int gm = blockIdx.x * 64;
    const int l15 = lane & 15;
    const int kgrp = lane >> 4;
    const int rgrp = kgrp * 4;
    const int laneoff = kgrp * 128 + l15 * 8;
    const int wquarter = wc * 4;

    floatx4 acc[4][4];
#pragma unroll
    for (int i = 0; i < 4; ++i)
#pragma unroll
        for (int j = 0; j < 4; ++j) acc[i][j] = (floatx4){0.f, 0.f, 0.f, 0.f};

    // ---------- stage 1: H = relu(A@W1+b1), double-buffered ----------
    long long aseg[4];
#pragma unroll
    for (int i = 0; i < 4; ++i) {
        int rt = (gm >> 4) + i;
        if (rt > M / 16 - 1) rt = M / 16 - 1;
        aseg[i] = (long long)rt * (K / 8) * 128;
    }

    {
        short8v afA[4], bhA[4], blA[4], afB[4], bhB[4], blB[4];
        S1_LOAD(afA, bhA, blA, 0);
#pragma unroll
        for (int k0 = 0; k0 < K; k0 += 64) {
            S1_LOAD(afB, bhB, blB, k0 + 32);
            DO_MFMA(afA, bhA, blA);
            if (k0 + 64 < K) S1_LOAD(afA, bhA, blA, k0 + 64);
            DO_MFMA(afB, bhB, blB);
        }
    }

    // write relu'd bf16 H tile into swizzled LDS [64][256]
#pragma unroll
    for (int j = 0; j < 4; ++j) {
        int col = wc * 64 + j * 16 + l15;
        float bb = b1[col];
#pragma unroll
        for (int i = 0; i < 4; ++i) {
            int lrow = i * 16 + rgrp;
#pragma unroll
            for (int r = 0; r < 4; ++r) {
                int row = lrow + r;
                float v = fmaxf(acc[i][j][r] + bb, 0.f);
                int bo = (row * 512 + col * 2) ^ ((row & 7) << 4);
                *(unsigned short*)(lds_raw + bo) = bf16_rne(v);
            }
        }
    }
    __syncthreads();

    // ---------- stage 2: out = H@W2+b2, double-buffered ----------
#pragma unroll
    for (int i = 0; i < 4; ++i)
#pragma unroll
        for (int j = 0; j < 4; ++j) acc[i][j] = (floatx4){0.f, 0.f, 0.f, 0.f};

    {
        short8v afA[4], bhA[4], blA[4], afB[4], bhB[4], blB[4];
        S2_LOAD(afA, bhA, blA, 0);
#pragma unroll
        for (int k0 = 0; k0 < HID_C; k0 += 64) {
            S2_LOAD(afB, bhB, blB, k0 + 32);
            DO_MFMA(afA, bhA, blA);
            if (k0 + 64 < HID_C) S2_LOAD(afA, bhA, blA, k0 + 64);
            DO_MFMA(afB, bhB, blB);
        }
    }

    // fused BN column sums (exact fp32 from accumulators)
#pragma unroll
    for (int j = 0; j < 4; ++j) {
        int col = wc * 64 + j * 16 + l15;
        float bb = b2[col];
        float s1 = 0.f, s2 = 0.f;
#pragma unroll
        for (int i = 0; i < 4; ++i) {
            int rowb = gm + i * 16 + rgrp;
#pragma unroll
            for (int r = 0; r < 4; ++r) {
                if (rowb + r < M) {
                    float v = acc[i][j][r] + bb;
                    s1 += v; s2 += v * v;
                }
            }
        }
        s1 += __shfl_xor(s1, 16); s1 += __shfl_xor(s1, 32);
        s2 += __shfl_xor(s2, 16); s2 += __shfl_xor(s2, 32);
        if ((lane >> 4) == 0) {
            atomicAdd(&bnsums[col], s1);
            atomicAdd(&bnsums[HID_C + col], s2);
        }
    }

    // coalesced bf16 epilogue via LDS (reuse lds_raw), 2 col-half phases
    unsigned short* stg = (unsigned short*)lds_raw;  // [64][132]
#pragma unroll
    for (int p = 0; p < 2; ++p) {
        __syncthreads();
        if ((wc >> 1) == p) {
#pragma unroll
            for (int j = 0; j < 4; ++j) {
                int col = wc * 64 + j * 16 + l15;
                int lcol = (wc & 1) * 64 + j * 16 + l15;
                float bb = b2[col];
#pragma unroll
                for (int i = 0; i < 4; ++i) {
                    int lrow = i * 16 + rgrp;
#pragma unroll
                    for (int r = 0; r < 4; ++r)
                        stg[(lrow + r) * 132 + lcol] = bf16_rne(acc[i][j][r] + bb);
                }
            }
        }
        __syncthreads();
#pragma unroll
        for (int it = 0; it < 8; ++it) {
            int idx = it * 256 + tid;
            int row = idx >> 5;
            int c4 = idx & 31;
            int grow = gm + row;
            if (grow < M)
                *(ushort4*)(outH + (long long)grow * HID_C + p * 128 + c4 * 4) =
                    *(const ushort4*)&stg[row * 132 + c4 * 4];
        }
    }
}

// ---------------- BatchNorm finalize ----------------
__global__ void bn_finalize(const float* __restrict__ sums, const float* __restrict__ gamma,
                            const float* __restrict__ beta, float* __restrict__ ss) {
    int f = threadIdx.x;
    float mean = sums[f] * (1.0f / M_NODES);
    float var = sums[HID_C + f] * (1.0f / M_NODES) - mean * mean;
    float sc = gamma[f] * rsqrtf(var + BN_EPS_C);
    ss[f] = sc;
    ss[HID_C + f] = beta[f] - mean * sc;
}

// ---------------- pooling (bf16 in, fused BN+relu) ----------------
#define POOL_BLOCKS 4096
#define POOL_RPB 25
__global__ void pool_bn(const unsigned short* __restrict__ h, const float* __restrict__ ss,
                        const int* __restrict__ batch, float* __restrict__ sums, int M) {
    int f = threadIdx.x;
    float sc = ss[f], sh = ss[HID_C + f];
    int r0 = blockIdx.x * POOL_RPB;
    if (r0 >= M) return;
    int r1 = r0 + POOL_RPB;
    if (r1 > M) r1 = M;
    int cur = batch[r0];
    float acc = 0.f;
    for (int r = r0; r < r1; ++r) {
        int g = batch[r];
        if (g != cur) {
            atomicAdd(&sums[(long long)cur * HID_C + f], acc);
            acc = 0.f;
            cur = g;
        }
        float v = bf16_to_f(h[(long long)r * HID_C + f]);
        acc += fmaxf(fmaf(v, sc, sh), 0.f);
    }
    atomicAdd(&sums[(long long)cur * HID_C + f], acc);
}

__device__ __forceinline__ int lower_bound_i(const int* a, int n, int v) {
    int lo = 0, hi = n;
    while (lo < hi) {
        int mid = (lo + hi) >> 1;
        if (a[mid] < v) lo = mid + 1;
        else hi = mid;
    }
    return lo;
}

__global__ void pool_finalize(const float* __restrict__ sums, const int* __restrict__ batch,
                              float* __restrict__ out) {
    int g = blockIdx.x, f = threadIdx.x;
    int lb = lower_bound_i(batch, M_NODES, g);
    int ub = lower_bound_i(batch, M_NODES, g + 1);
    float cnt = (float)(ub - lb);
    out[(long long)g * HID_C + f] = sums[(long long)g * HID_C + f] / fmaxf(cnt, 1.0f);
}

// ---------------- launch ----------------
extern "C" void kernel_launch(void* const* d_in, const int* in_sizes, int n_in,
                              void* d_out, int out_size, void* d_ws, size_t ws_size,
                              hipStream_t stream) {
    const float* x = (const float*)d_in[0];
    const int* ei = (const int*)d_in[1];
    const int* esrc = ei;
    const int* edst = ei + N_EDGES_C;
    const int* batch = (const int*)d_in[2];
    const float* W1_0 = (const float*)d_in[3];
    const float* b1_0 = (const float*)d_in[4];
    const float* W2_0 = (const float*)d_in[5];
    const float* b2_0 = (const float*)d_in[6];
    const float* g0 = (const float*)d_in[7];
    const float* be0 = (const float*)d_in[8];
    const float* W1_1 = (const float*)d_in[9];
    const float* b1_1 = (const float*)d_in[10];
    const float* W2_1 = (const float*)d_in[11];
    const float* b2_1 = (const float*)d_in[12];
    const float* g1 = (const float*)d_in[13];
    const float* be1 = (const float*)d_in[14];
    float* out = (float*)d_out;

    const long long NF = (long long)M_NODES * HID_C;
    const long long NI = (long long)M_NODES * IN_DIM_C;
    unsigned short* U = (unsigned short*)d_ws;
    unsigned short* X16 = U;
    unsigned short* A0 = U + NI;
    unsigned short* Hb0 = U + 2 * NI;
    unsigned short* A1 = Hb0 + NF;
    unsigned short* Hb1 = A1 + NF;
    float* fbase = (float*)(Hb1 + NF);
    float* bns = fbase;
    float* ss0 = bns + 2 * HID_C;
    float* ss1 = ss0 + 2 * HID_C;
    float* psum = ss1 + 2 * HID_C;
    int* counts = (int*)(psum + N_GRAPHS_C * HID_C);
    int* partials = counts + 100352;
    int* rowptr = partials + 512;
    int* csr_src = rowptr + 100004;
    unsigned short* wp = (unsigned short*)(csr_src + N_EDGES_C);
    unsigned short* wAh = wp;
    unsigned short* wAl = wAh + IN_DIM_C * HID_C;
    unsigned short* wBh = wAl + IN_DIM_C * HID_C;
    unsigned short* wBl = wBh + HID_C * HID_C;
    unsigned short* wCh = wBl + HID_C * HID_C;
    unsigned short* wCl = wCh + HID_C * HID_C;
    unsigned short* wDh = wCl + HID_C * HID_C;
    unsigned short* wDl = wDh + HID_C * HID_C;

    dim3 blk(256);
    dim3 fgrid((M_NODES + 63) / 64);

    // ---- W splits (fragment-major) ----
    wsplit<IN_DIM_C><<<(IN_DIM_C * HID_C + 255) / 256, blk, 0, stream>>>(W1_0, wAh, wAl);
    wsplit<HID_C><<<(HID_C * HID_C + 255) / 256, blk, 0, stream>>>(W2_0, wBh, wBl);
    wsplit<HID_C><<<(HID_C * HID_C + 255) / 256, blk, 0, stream>>>(W1_1, wCh, wCl);
    wsplit<HID_C><<<(HID_C * HID_C + 255) / 256, blk, 0, stream>>>(W2_1, wDh, wDl);

    // ---- CSR build ----
    zero_i<<<(M_NODES + 255) / 256, blk, 0, stream>>>(counts, M_NODES);
    csr_count<<<(N_EDGES_C + 255) / 256, blk, 0, stream>>>(edst, counts);
    block_scan<<<392, blk, 0, stream>>>(counts, rowptr, partials);
    scan_partials<<<1, 512, 0, stream>>>(partials, 392);
    add_offsets<<<392, blk, 0, stream>>>(rowptr, partials);
    copy_i<<<(M_NODES + 255) / 256, blk, 0, stream>>>(rowptr, counts, M_NODES);
    csr_fill<<<(N_EDGES_C + 255) / 256, blk, 0, stream>>>(esrc, edst, counts, csr_src);

    // ---- x -> bf16 ----
    f2b<<<(int)((NI / 4 + 255) / 256), blk, 0, stream>>>((const float4*)x, (ushort4*)X16,
                                                         (int)(NI / 4));

    // ---- Layer 0 ----
    gather_frag<IN_DIM_C, false><<<M_NODES / 16, blk, 0, stream>>>(X16, rowptr, csr_src,
                                                                   nullptr, A0);
    zero_f<<<2, blk, 0, stream>>>(bns, 2 * HID_C);
    fused_mlp<IN_DIM_C><<<fgrid, blk, 0, stream>>>(A0, wAh, wAl, b1_0, wBh, wBl, b2_0,
                                                   Hb0, M_NODES, bns);
    bn_finalize<<<1, blk, 0, stream>>>(bns, g0, be0, ss0);

    // ---- Layer 1 ----
    gather_frag<HID_C, true><<<M_NODES / 16, blk, 0, stream>>>(Hb0, rowptr, csr_src,
                                                               ss0, A1);
    zero_f<<<2, blk, 0, stream>>>(bns, 2 * HID_C);
    fused_mlp<HID_C><<<fgrid, blk, 0, stream>>>(A1, wCh, wCl, b1_1, wDh, wDl, b2_1,
                                                Hb1, M_NODES, bns);
    bn_finalize<<<1, blk, 0, stream>>>(bns, g1, be1, ss1);

    // ---- Pool (fused BN+relu) ----
    zero_f<<<(N_GRAPHS_C * HID_C + 255) / 256, blk, 0, stream>>>(psum, N_GRAPHS_C * HID_C);
    pool_bn<<<POOL_BLOCKS, blk, 0, stream>>>(Hb1, ss1, batch, psum, M_NODES);
    pool_finalize<<<256, blk, 0, stream>>>(psum, batch, out);
}

// Round 11
// 443.594 us; speedup vs baseline: 1.0722x; 1.0722x over previous
//
#include <hip/hip_runtime.h>

#define M_NODES 100000
#define N_EDGES_C 800000
#define IN_DIM_C 128
#define HID_C 256
#define N_GRAPHS_C 256
#define BN_EPS_C 1e-5f

typedef __attribute__((ext_vector_type(8))) short short8v;
typedef __attribute__((ext_vector_type(4))) float floatx4;

__device__ __forceinline__ unsigned short bf16_rne(float f) {
    union { float f; unsigned u; } x; x.f = f;
    unsigned r = x.u + 0x7FFF + ((x.u >> 16) & 1);
    return (unsigned short)(r >> 16);
}
__device__ __forceinline__ float bf16_to_f(unsigned short h) {
    union { unsigned u; float f; } x; x.u = ((unsigned)h) << 16;
    return x.f;
}
__device__ __forceinline__ float bf16lo_f(unsigned u) {
    union { unsigned u; float f; } x; x.u = u << 16;
    return x.f;
}
__device__ __forceinline__ float bf16hi_f(unsigned u) {
    union { unsigned u; float f; } x; x.u = u & 0xffff0000u;
    return x.f;
}

// fragment-major W offset
template <int K>
__device__ __forceinline__ long long woff(int c, int k) {
    return ((long long)((k >> 5) * 16 + (c >> 4))) * 512 + ((k >> 3) & 3) * 128 +
           (c & 15) * 8 + (k & 7);
}

template <int N8>
__device__ __forceinline__ void loadU(const unsigned short* p, unsigned* w) {
#pragma unroll
    for (int c = 0; c < N8; ++c) {
        uint4 u = *(const uint4*)(p + c * 8);
        w[c * 4 + 0] = u.x; w[c * 4 + 1] = u.y; w[c * 4 + 2] = u.z; w[c * 4 + 3] = u.w;
    }
}

// ---------------- small helpers ----------------
__global__ void zero_f(float* __restrict__ p, int n) {
    int i = blockIdx.x * blockDim.x + threadIdx.x;
    if (i < n) p[i] = 0.f;
}
__global__ void zero_i(int* __restrict__ p, int n) {
    int i = blockIdx.x * blockDim.x + threadIdx.x;
    if (i < n) p[i] = 0;
}
__global__ void copy_i(const int* __restrict__ s, int* __restrict__ d, int n) {
    int i = blockIdx.x * blockDim.x + threadIdx.x;
    if (i < n) d[i] = s[i];
}
__global__ void f2b(const float4* __restrict__ in, ushort4* __restrict__ out, int n4) {
    int i = blockIdx.x * blockDim.x + threadIdx.x;
    if (i >= n4) return;
    float4 v = in[i];
    ushort4 o;
    o.x = bf16_rne(v.x); o.y = bf16_rne(v.y); o.z = bf16_rne(v.z); o.w = bf16_rne(v.w);
    out[i] = o;
}

// ---------------- W split -> fragment-major hi/lo planes ----------------
template <int K>
__global__ void wsplit(const float* __restrict__ W, unsigned short* __restrict__ hi,
                       unsigned short* __restrict__ lo) {
    int t = blockIdx.x * blockDim.x + threadIdx.x;
    if (t >= K * HID_C) return;
    int k = t % K, c = t / K;
    float w = W[(long long)k * HID_C + c];
    unsigned short h = bf16_rne(w);
    unsigned short l = bf16_rne(w - bf16_to_f(h));
    long long o = woff<K>(c, k);
    hi[o] = h;
    lo[o] = l;
}

// ---------------- CSR build ----------------
__global__ void csr_count(const int* __restrict__ dst, int* __restrict__ counts) {
    int e = blockIdx.x * blockDim.x + threadIdx.x;
    if (e < N_EDGES_C) atomicAdd(&counts[dst[e]], 1);
}

__global__ __launch_bounds__(256) void block_scan(const int* __restrict__ counts,
                                                  int* __restrict__ excl,
                                                  int* __restrict__ partials) {
    __shared__ int sm[256];
    int i = blockIdx.x * 256 + threadIdx.x;
    int v = (i < M_NODES) ? counts[i] : 0;
    sm[threadIdx.x] = v;
    __syncthreads();
    for (int off = 1; off < 256; off <<= 1) {
        int add = (threadIdx.x >= off) ? sm[threadIdx.x - off] : 0;
        __syncthreads();
        sm[threadIdx.x] += add;
        __syncthreads();
    }
    if (i <= M_NODES) excl[i] = sm[threadIdx.x] - v;
    if (threadIdx.x == 255) partials[blockIdx.x] = sm[255];
}

__global__ __launch_bounds__(512) void scan_partials(int* __restrict__ partials, int nb) {
    __shared__ int sm[512];
    int t = threadIdx.x;
    int v = (t < nb) ? partials[t] : 0;
    sm[t] = v;
    __syncthreads();
    for (int off = 1; off < 512; off <<= 1) {
        int add = (t >= off) ? sm[t - off] : 0;
        __syncthreads();
        sm[t] += add;
        __syncthreads();
    }
    if (t < nb) partials[t] = sm[t] - v;
}

__global__ void add_offsets(int* __restrict__ rowptr, const int* __restrict__ partials) {
    int i = blockIdx.x * 256 + threadIdx.x;
    if (i <= M_NODES) rowptr[i] += partials[blockIdx.x];
}

__global__ void csr_fill(const int* __restrict__ src, const int* __restrict__ dst,
                         int* __restrict__ fillpos, int* __restrict__ csr_src) {
    int e = blockIdx.x * blockDim.x + threadIdx.x;
    if (e >= N_EDGES_C) return;
    int pos = atomicAdd(&fillpos[dst[e]], 1);
    csr_src[pos] = src[e];
}

// ---------------- fused GNN layer: gather -> MLP -> pre-BN bf16 out + BN col sums ----------------
// Phase G: gather 64 rows (optional BN+relu of prev layer) into swizzled LDS A-tile.
// Stage 1: H = relu(A@W1+b1) -> overwrite LDS with H. Stage 2: out = H@W2+b2.
template <int K, bool BN>
__global__ __launch_bounds__(256, 4) void fused_gnn(const unsigned short* __restrict__ Hin,
                                                    const int* __restrict__ rowptr,
                                                    const int* __restrict__ csr_src,
                                                    const float* __restrict__ ss,
                                                    const unsigned short* __restrict__ W1h,
                                                    const unsigned short* __restrict__ W1l,
                                                    const float* __restrict__ b1,
                                                    const unsigned short* __restrict__ W2h,
                                                    const unsigned short* __restrict__ W2l,
                                                    const float* __restrict__ b2,
                                                    unsigned short* __restrict__ outH,
                                                    int M, float* __restrict__ bnsums) {
    __shared__ char lds_raw[32768];  // A tile [64][K] then H tile [64][256], XOR-swizzled

    const int tid = threadIdx.x;
    const int lane = tid & 63;
    const int wc = tid >> 6;
    const int gm = blockIdx.x * 64;
    const int l15 = lane & 15;
    const int kgrp = lane >> 4;
    const int rgrp = kgrp * 4;
    const int laneoff = kgrp * 128 + l15 * 8;
    const int wquarter = wc * 4;

    // ---------- phase G: gather into LDS A ----------
    {
        constexpr int FPT = K / 16;   // feats per thread (8 or 16)
        const int fq = tid & 15;
        const int f0 = fq * FPT;
#pragma unroll
        for (int it = 0; it < 4; ++it) {
            int nl = it * 16 + (tid >> 4);
            int node = gm + nl;
            int nc = node < M ? node : M - 1;
            int beg = rowptr[nc], end = rowptr[nc + 1];
            float a[FPT], sc[FPT], sh[FPT];
            if (BN) {
#pragma unroll
                for (int i = 0; i < FPT; ++i) {
                    sc[i] = ss[f0 + i];
                    sh[i] = ss[HID_C + f0 + i];
                }
            }
            {
                unsigned w[FPT / 2];
                loadU<FPT / 8>(Hin + (long long)nc * K + f0, w);
#pragma unroll
                for (int i = 0; i < FPT / 2; ++i) {
                    float lo = bf16lo_f(w[i]), hi = bf16hi_f(w[i]);
                    a[2 * i] = BN ? fmaxf(fmaf(lo, sc[2 * i], sh[2 * i]), 0.f) : lo;
                    a[2 * i + 1] = BN ? fmaxf(fmaf(hi, sc[2 * i + 1], sh[2 * i + 1]), 0.f) : hi;
                }
            }
            for (int e = beg; e < end; ++e) {
                long long s = csr_src[e];
                unsigned w[FPT / 2];
                loadU<FPT / 8>(Hin + s * K + f0, w);
#pragma unroll
                for (int i = 0; i < FPT / 2; ++i) {
                    float lo = bf16lo_f(w[i]), hi = bf16hi_f(w[i]);
                    a[2 * i] += BN ? fmaxf(fmaf(lo, sc[2 * i], sh[2 * i]), 0.f) : lo;
                    a[2 * i + 1] += BN ? fmaxf(fmaf(hi, sc[2 * i + 1], sh[2 * i + 1]), 0.f) : hi;
                }
            }
#pragma unroll
            for (int c = 0; c < FPT / 8; ++c) {
                uint4 v;
                v.x = (unsigned)bf16_rne(a[c * 8 + 0]) | ((unsigned)bf16_rne(a[c * 8 + 1]) << 16);
                v.y = (unsigned)bf16_rne(a[c * 8 + 2]) | ((unsigned)bf16_rne(a[c * 8 + 3]) << 16);
                v.z = (unsigned)bf16_rne(a[c * 8 + 4]) | ((unsigned)bf16_rne(a[c * 8 + 5]) << 16);
                v.w = (unsigned)bf16_rne(a[c * 8 + 6]) | ((unsigned)bf16_rne(a[c * 8 + 7]) << 16);
                int col = f0 + c * 8;
                int bo = (nl * (K * 2) + col * 2) ^ ((nl & 7) << 4);
                *(uint4*)(lds_raw + bo) = v;
            }
        }
    }
    __syncthreads();

    floatx4 acc[4][4];
#pragma unroll
    for (int i = 0; i < 4; ++i)
#pragma unroll
        for (int j = 0; j < 4; ++j) acc[i][j] = (floatx4){0.f, 0.f, 0.f, 0.f};

    // ---------- stage 1: H = relu(A@W1+b1), A from LDS ----------
#pragma unroll
    for (int k0 = 0; k0 < K; k0 += 32) {
        short8v af[4], bh[4], bl[4];
#pragma unroll
        for (int i = 0; i < 4; ++i) {
            int row = i * 16 + l15;
            int bo = (row * (K * 2) + (k0 + kgrp * 8) * 2) ^ ((row & 7) << 4);
            af[i] = *(const short8v*)(lds_raw + bo);
        }
#pragma unroll
        for (int j = 0; j < 4; ++j) {
            long long wb = (long long)(k0 >> 5) * 8192 + (wquarter + j) * 512 + laneoff;
            bh[j] = *(const short8v*)(W1h + wb);
            bl[j] = *(const short8v*)(W1l + wb);
        }
#pragma unroll
        for (int i = 0; i < 4; ++i)
#pragma unroll
            for (int j = 0; j < 4; ++j) {
                acc[i][j] = __builtin_amdgcn_mfma_f32_16x16x32_bf16(af[i], bh[j], acc[i][j], 0, 0, 0);
                acc[i][j] = __builtin_amdgcn_mfma_f32_16x16x32_bf16(af[i], bl[j], acc[i][j], 0, 0, 0);
            }
    }
    __syncthreads();  // A fully consumed; safe to overwrite with H

    // write relu'd bf16 H tile into swizzled LDS [64][256]
#pragma unroll
    for (int j = 0; j < 4; ++j) {
        int col = wc * 64 + j * 16 + l15;
        float bb = b1[col];
#pragma unroll
        for (int i = 0; i < 4; ++i) {
            int lrow = i * 16 + rgrp;
#pragma unroll
            for (int r = 0; r < 4; ++r) {
                int row = lrow + r;
                float v = fmaxf(acc[i][j][r] + bb, 0.f);
                int bo = (row * 512 + col * 2) ^ ((row & 7) << 4);
                *(unsigned short*)(lds_raw + bo) = bf16_rne(v);
            }
        }
    }
    __syncthreads();

    // ---------- stage 2: out = H@W2+b2 ----------
#pragma unroll
    for (int i = 0; i < 4; ++i)
#pragma unroll
        for (int j = 0; j < 4; ++j) acc[i][j] = (floatx4){0.f, 0.f, 0.f, 0.f};

#pragma unroll
    for (int k0 = 0; k0 < HID_C; k0 += 32) {
        short8v af[4], bh[4], bl[4];
#pragma unroll
        for (int i = 0; i < 4; ++i) {
            int row = i * 16 + l15;
            int bo = (row * 512 + (k0 + kgrp * 8) * 2) ^ ((row & 7) << 4);
            af[i] = *(const short8v*)(lds_raw + bo);
        }
#pragma unroll
        for (int j = 0; j < 4; ++j) {
            long long wb = (long long)(k0 >> 5) * 8192 + (wquarter + j) * 512 + laneoff;
            bh[j] = *(const short8v*)(W2h + wb);
            bl[j] = *(const short8v*)(W2l + wb);
        }
#pragma unroll
        for (int i = 0; i < 4; ++i)
#pragma unroll
            for (int j = 0; j < 4; ++j) {
                acc[i][j] = __builtin_amdgcn_mfma_f32_16x16x32_bf16(af[i], bh[j], acc[i][j], 0, 0, 0);
                acc[i][j] = __builtin_amdgcn_mfma_f32_16x16x32_bf16(af[i], bl[j], acc[i][j], 0, 0, 0);
            }
    }

    // fused BN column sums (exact fp32 from accumulators)
#pragma unroll
    for (int j = 0; j < 4; ++j) {
        int col = wc * 64 + j * 16 + l15;
        float bb = b2[col];
        float s1 = 0.f, s2 = 0.f;
#pragma unroll
        for (int i = 0; i < 4; ++i) {
            int rowb = gm + i * 16 + rgrp;
#pragma unroll
            for (int r = 0; r < 4; ++r) {
                if (rowb + r < M) {
                    float v = acc[i][j][r] + bb;
                    s1 += v; s2 += v * v;
                }
            }
        }
        s1 += __shfl_xor(s1, 16); s1 += __shfl_xor(s1, 32);
        s2 += __shfl_xor(s2, 16); s2 += __shfl_xor(s2, 32);
        if ((lane >> 4) == 0) {
            atomicAdd(&bnsums[col], s1);
            atomicAdd(&bnsums[HID_C + col], s2);
        }
    }

    // coalesced bf16 epilogue via LDS (reuse lds_raw), 2 col-half phases
    unsigned short* stg = (unsigned short*)lds_raw;  // [64][132]
#pragma unroll
    for (int p = 0; p < 2; ++p) {
        __syncthreads();
        if ((wc >> 1) == p) {
#pragma unroll
            for (int j = 0; j < 4; ++j) {
                int col = wc * 64 + j * 16 + l15;
                int lcol = (wc & 1) * 64 + j * 16 + l15;
                float bb = b2[col];
#pragma unroll
                for (int i = 0; i < 4; ++i) {
                    int lrow = i * 16 + rgrp;
#pragma unroll
                    for (int r = 0; r < 4; ++r)
                        stg[(lrow + r) * 132 + lcol] = bf16_rne(acc[i][j][r] + bb);
                }
            }
        }
        __syncthreads();
#pragma unroll
        for (int it = 0; it < 8; ++it) {
            int idx = it * 256 + tid;
            int row = idx >> 5;
            int c4 = idx & 31;
            int grow = gm + row;
            if (grow < M)
                *(ushort4*)(outH + (long long)grow * HID_C + p * 128 + c4 * 4) =
                    *(const ushort4*)&stg[row * 132 + c4 * 4];
        }
    }
}

// ---------------- BatchNorm finalize ----------------
__global__ void bn_finalize(const float* __restrict__ sums, const float* __restrict__ gamma,
                            const float* __restrict__ beta, float* __restrict__ ss) {
    int f = threadIdx.x;
    float mean = sums[f] * (1.0f / M_NODES);
    float var = sums[HID_C + f] * (1.0f / M_NODES) - mean * mean;
    float sc = gamma[f] * rsqrtf(var + BN_EPS_C);
    ss[f] = sc;
    ss[HID_C + f] = beta[f] - mean * sc;
}

// ---------------- pooling (bf16 in, fused BN+relu) ----------------
#define POOL_BLOCKS 4096
#define POOL_RPB 25
__global__ void pool_bn(const unsigned short* __restrict__ h, const float* __restrict__ ss,
                        const int* __restrict__ batch, float* __restrict__ sums, int M) {
    int f = threadIdx.x;
    float sc = ss[f], sh = ss[HID_C + f];
    int r0 = blockIdx.x * POOL_RPB;
    if (r0 >= M) return;
    int r1 = r0 + POOL_RPB;
    if (r1 > M) r1 = M;
    int cur = batch[r0];
    float acc = 0.f;
    for (int r = r0; r < r1; ++r) {
        int g = batch[r];
        if (g != cur) {
            atomicAdd(&sums[(long long)cur * HID_C + f], acc);
            acc = 0.f;
            cur = g;
        }
        float v = bf16_to_f(h[(long long)r * HID_C + f]);
        acc += fmaxf(fmaf(v, sc, sh), 0.f);
    }
    atomicAdd(&sums[(long long)cur * HID_C + f], acc);
}

__device__ __forceinline__ int lower_bound_i(const int* a, int n, int v) {
    int lo = 0, hi = n;
    while (lo < hi) {
        int mid = (lo + hi) >> 1;
        if (a[mid] < v) lo = mid + 1;
        else hi = mid;
    }
    return lo;
}

__global__ void pool_finalize(const float* __restrict__ sums, const int* __restrict__ batch,
                              float* __restrict__ out) {
    int g = blockIdx.x, f = threadIdx.x;
    int lb = lower_bound_i(batch, M_NODES, g);
    int ub = lower_bound_i(batch, M_NODES, g + 1);
    float cnt = (float)(ub - lb);
    out[(long long)g * HID_C + f] = sums[(long long)g * HID_C + f] / fmaxf(cnt, 1.0f);
}

// ---------------- launch ----------------
extern "C" void kernel_launch(void* const* d_in, const int* in_sizes, int n_in,
                              void* d_out, int out_size, void* d_ws, size_t ws_size,
                              hipStream_t stream) {
    const float* x = (const float*)d_in[0];
    const int* ei = (const int*)d_in[1];
    const int* esrc = ei;
    const int* edst = ei + N_EDGES_C;
    const int* batch = (const int*)d_in[2];
    const float* W1_0 = (const float*)d_in[3];
    const float* b1_0 = (const float*)d_in[4];
    const float* W2_0 = (const float*)d_in[5];
    const float* b2_0 = (const float*)d_in[6];
    const float* g0 = (const float*)d_in[7];
    const float* be0 = (const float*)d_in[8];
    const float* W1_1 = (const float*)d_in[9];
    const float* b1_1 = (const float*)d_in[10];
    const float* W2_1 = (const float*)d_in[11];
    const float* b2_1 = (const float*)d_in[12];
    const float* g1 = (const float*)d_in[13];
    const float* be1 = (const float*)d_in[14];
    float* out = (float*)d_out;

    const long long NF = (long long)M_NODES * HID_C;
    const long long NI = (long long)M_NODES * IN_DIM_C;
    unsigned short* U = (unsigned short*)d_ws;
    unsigned short* X16 = U;           // NI  (bf16 x)
    unsigned short* Hb0 = U + NI;      // NF  (pre-BN out L0)
    unsigned short* Hb1 = Hb0 + NF;    // NF  (pre-BN out L1)
    float* fbase = (float*)(Hb1 + NF);
    float* bns = fbase;
    float* ss0 = bns + 2 * HID_C;
    float* ss1 = ss0 + 2 * HID_C;
    float* psum = ss1 + 2 * HID_C;
    int* counts = (int*)(psum + N_GRAPHS_C * HID_C);
    int* partials = counts + 100352;
    int* rowptr = partials + 512;
    int* csr_src = rowptr + 100004;
    unsigned short* wp = (unsigned short*)(csr_src + N_EDGES_C);
    unsigned short* wAh = wp;
    unsigned short* wAl = wAh + IN_DIM_C * HID_C;
    unsigned short* wBh = wAl + IN_DIM_C * HID_C;
    unsigned short* wBl = wBh + HID_C * HID_C;
    unsigned short* wCh = wBl + HID_C * HID_C;
    unsigned short* wCl = wCh + HID_C * HID_C;
    unsigned short* wDh = wCl + HID_C * HID_C;
    unsigned short* wDl = wDh + HID_C * HID_C;

    dim3 blk(256);
    dim3 fgrid((M_NODES + 63) / 64);

    // ---- W splits (fragment-major) ----
    wsplit<IN_DIM_C><<<(IN_DIM_C * HID_C + 255) / 256, blk, 0, stream>>>(W1_0, wAh, wAl);
    wsplit<HID_C><<<(HID_C * HID_C + 255) / 256, blk, 0, stream>>>(W2_0, wBh, wBl);
    wsplit<HID_C><<<(HID_C * HID_C + 255) / 256, blk, 0, stream>>>(W1_1, wCh, wCl);
    wsplit<HID_C><<<(HID_C * HID_C + 255) / 256, blk, 0, stream>>>(W2_1, wDh, wDl);

    // ---- CSR build ----
    zero_i<<<(M_NODES + 255) / 256, blk, 0, stream>>>(counts, M_NODES);
    csr_count<<<(N_EDGES_C + 255) / 256, blk, 0, stream>>>(edst, counts);
    block_scan<<<392, blk, 0, stream>>>(counts, rowptr, partials);
    scan_partials<<<1, 512, 0, stream>>>(partials, 392);
    add_offsets<<<392, blk, 0, stream>>>(rowptr, partials);
    copy_i<<<(M_NODES + 255) / 256, blk, 0, stream>>>(rowptr, counts, M_NODES);
    csr_fill<<<(N_EDGES_C + 255) / 256, blk, 0, stream>>>(esrc, edst, counts, csr_src);

    // ---- x -> bf16 ----
    f2b<<<(int)((NI / 4 + 255) / 256), blk, 0, stream>>>((const float4*)x, (ushort4*)X16,
                                                         (int)(NI / 4));

    // ---- Layer 0 (gather fused) ----
    zero_f<<<2, blk, 0, stream>>>(bns, 2 * HID_C);
    fused_gnn<IN_DIM_C, false><<<fgrid, blk, 0, stream>>>(X16, rowptr, csr_src, nullptr,
                                                          wAh, wAl, b1_0, wBh, wBl, b2_0,
                                                          Hb0, M_NODES, bns);
    bn_finalize<<<1, blk, 0, stream>>>(bns, g0, be0, ss0);

    // ---- Layer 1 (gather fused, prev-BN applied in gather) ----
    zero_f<<<2, blk, 0, stream>>>(bns, 2 * HID_C);
    fused_gnn<HID_C, true><<<fgrid, blk, 0, stream>>>(Hb0, rowptr, csr_src, ss0,
                                                      wCh, wCl, b1_1, wDh, wDl, b2_1,
                                                      Hb1, M_NODES, bns);
    bn_finalize<<<1, blk, 0, stream>>>(bns, g1, be1, ss1);

    // ---- Pool (fused BN+relu) ----
    zero_f<<<(N_GRAPHS_C * HID_C + 255) / 256, blk, 0, stream>>>(psum, N_GRAPHS_C * HID_C);
    pool_bn<<<POOL_BLOCKS, blk, 0, stream>>>(Hb1, ss1, batch, psum, M_NODES);
    pool_finalize<<<256, blk, 0, stream>>>(psum, batch, out);
}

// Round 12
// 417.554 us; speedup vs baseline: 1.1391x; 1.0624x over previous
//
#include <hip/hip_runtime.h>

#define M_NODES 100000
#define N_EDGES_C 800000
#define IN_DIM_C 128
#define HID_C 256
#define N_GRAPHS_C 256
#define BN_EPS_C 1e-5f

typedef __attribute__((ext_vector_type(8))) short short8v;
typedef __attribute__((ext_vector_type(4))) float floatx4;

__device__ __forceinline__ unsigned short bf16_rne(float f) {
    union { float f; unsigned u; } x; x.f = f;
    unsigned r = x.u + 0x7FFF + ((x.u >> 16) & 1);
    return (unsigned short)(r >> 16);
}
__device__ __forceinline__ float bf16_to_f(unsigned short h) {
    union { unsigned u; float f; } x; x.u = ((unsigned)h) << 16;
    return x.f;
}
__device__ __forceinline__ float bf16lo_f(unsigned u) {
    union { unsigned u; float f; } x; x.u = u << 16;
    return x.f;
}
__device__ __forceinline__ float bf16hi_f(unsigned u) {
    union { unsigned u; float f; } x; x.u = u & 0xffff0000u;
    return x.f;
}

// fragment-major W offset
template <int K>
__device__ __forceinline__ long long woff(int c, int k) {
    return ((long long)((k >> 5) * 16 + (c >> 4))) * 512 + ((k >> 3) & 3) * 128 +
           (c & 15) * 8 + (k & 7);
}

template <int N8>
__device__ __forceinline__ void loadU(const unsigned short* p, unsigned* w) {
#pragma unroll
    for (int c = 0; c < N8; ++c) {
        uint4 u = *(const uint4*)(p + c * 8);
        w[c * 4 + 0] = u.x; w[c * 4 + 1] = u.y; w[c * 4 + 2] = u.z; w[c * 4 + 3] = u.w;
    }
}

// ---------------- small helpers ----------------
__global__ void zero_f(float* __restrict__ p, int n) {
    int i = blockIdx.x * blockDim.x + threadIdx.x;
    if (i < n) p[i] = 0.f;
}
__global__ void zero_i(int* __restrict__ p, int n) {
    int i = blockIdx.x * blockDim.x + threadIdx.x;
    if (i < n) p[i] = 0;
}
__global__ void copy_i(const int* __restrict__ s, int* __restrict__ d, int n) {
    int i = blockIdx.x * blockDim.x + threadIdx.x;
    if (i < n) d[i] = s[i];
}
__global__ void f2b(const float4* __restrict__ in, ushort4* __restrict__ out, int n4) {
    int i = blockIdx.x * blockDim.x + threadIdx.x;
    if (i >= n4) return;
    float4 v = in[i];
    ushort4 o;
    o.x = bf16_rne(v.x); o.y = bf16_rne(v.y); o.z = bf16_rne(v.z); o.w = bf16_rne(v.w);
    out[i] = o;
}

// ---------------- W -> fragment-major, dual-plane (hi/lo) ----------------
template <int K>
__global__ void wsplit(const float* __restrict__ W, unsigned short* __restrict__ hi,
                       unsigned short* __restrict__ lo) {
    int t = blockIdx.x * blockDim.x + threadIdx.x;
    if (t >= K * HID_C) return;
    int k = t % K, c = t / K;
    float w = W[(long long)k * HID_C + c];
    unsigned short h = bf16_rne(w);
    unsigned short l = bf16_rne(w - bf16_to_f(h));
    long long o = woff<K>(c, k);
    hi[o] = h;
    lo[o] = l;
}

// ---------------- W -> fragment-major, single-plane (rounded bf16) ----------------
template <int K>
__global__ void wpack(const float* __restrict__ W, unsigned short* __restrict__ hi) {
    int t = blockIdx.x * blockDim.x + threadIdx.x;
    if (t >= K * HID_C) return;
    int k = t % K, c = t / K;
    hi[woff<K>(c, k)] = bf16_rne(W[(long long)k * HID_C + c]);
}

// ---------------- CSR build ----------------
__global__ void csr_count(const int* __restrict__ dst, int* __restrict__ counts) {
    int e = blockIdx.x * blockDim.x + threadIdx.x;
    if (e < N_EDGES_C) atomicAdd(&counts[dst[e]], 1);
}

__global__ __launch_bounds__(256) void block_scan(const int* __restrict__ counts,
                                                  int* __restrict__ excl,
                                                  int* __restrict__ partials) {
    __shared__ int sm[256];
    int i = blockIdx.x * 256 + threadIdx.x;
    int v = (i < M_NODES) ? counts[i] : 0;
    sm[threadIdx.x] = v;
    __syncthreads();
    for (int off = 1; off < 256; off <<= 1) {
        int add = (threadIdx.x >= off) ? sm[threadIdx.x - off] : 0;
        __syncthreads();
        sm[threadIdx.x] += add;
        __syncthreads();
    }
    if (i <= M_NODES) excl[i] = sm[threadIdx.x] - v;
    if (threadIdx.x == 255) partials[blockIdx.x] = sm[255];
}

__global__ __launch_bounds__(512) void scan_partials(int* __restrict__ partials, int nb) {
    __shared__ int sm[512];
    int t = threadIdx.x;
    int v = (t < nb) ? partials[t] : 0;
    sm[t] = v;
    __syncthreads();
    for (int off = 1; off < 512; off <<= 1) {
        int add = (t >= off) ? sm[t - off] : 0;
        __syncthreads();
        sm[t] += add;
        __syncthreads();
    }
    if (t < nb) partials[t] = sm[t] - v;
}

__global__ void add_offsets(int* __restrict__ rowptr, const int* __restrict__ partials) {
    int i = blockIdx.x * 256 + threadIdx.x;
    if (i <= M_NODES) rowptr[i] += partials[blockIdx.x];
}

__global__ void csr_fill(const int* __restrict__ src, const int* __restrict__ dst,
                         int* __restrict__ fillpos, int* __restrict__ csr_src) {
    int e = blockIdx.x * blockDim.x + threadIdx.x;
    if (e >= N_EDGES_C) return;
    int pos = atomicAdd(&fillpos[dst[e]], 1);
    csr_src[pos] = src[e];
}

// ---------------- fused GNN layer: gather -> MLP -> pre-BN bf16 out + BN col sums ----------------
// Phase G: gather 64 rows (optional BN+relu of prev layer) into swizzled LDS A-tile.
// Stage 1: H = relu(A@W1+b1), W1 single-plane -> overwrite LDS with H.
// Stage 2: out = H@(W2h+W2l)+b2 (dual-plane, accuracy-critical).
template <int K, bool BN>
__global__ __launch_bounds__(256, 4) void fused_gnn(const unsigned short* __restrict__ Hin,
                                                    const int* __restrict__ rowptr,
                                                    const int* __restrict__ csr_src,
                                                    const float* __restrict__ ss,
                                                    const unsigned short* __restrict__ W1,
                                                    const float* __restrict__ b1,
                                                    const unsigned short* __restrict__ W2h,
                                                    const unsigned short* __restrict__ W2l,
                                                    const float* __restrict__ b2,
                                                    unsigned short* __restrict__ outH,
                                                    int M, float* __restrict__ bnsums) {
    __shared__ char lds_raw[32768];  // A tile [64][K] then H tile [64][256], XOR-swizzled

    const int tid = threadIdx.x;
    const int lane = tid & 63;
    const int wc = tid >> 6;
    const int gm = blockIdx.x * 64;
    const int l15 = lane & 15;
    const int kgrp = lane >> 4;
    const int rgrp = kgrp * 4;
    const int laneoff = kgrp * 128 + l15 * 8;
    const int wquarter = wc * 4;

    // ---------- phase G: gather into LDS A ----------
    {
        constexpr int FPT = K / 16;   // feats per thread (8 or 16)
        const int fq = tid & 15;
        const int f0 = fq * FPT;
#pragma unroll
        for (int it = 0; it < 4; ++it) {
            int nl = it * 16 + (tid >> 4);
            int node = gm + nl;
            int nc = node < M ? node : M - 1;
            int beg = rowptr[nc], end = rowptr[nc + 1];
            float a[FPT], sc[FPT], sh[FPT];
            if (BN) {
#pragma unroll
                for (int i = 0; i < FPT; ++i) {
                    sc[i] = ss[f0 + i];
                    sh[i] = ss[HID_C + f0 + i];
                }
            }
            {
                unsigned w[FPT / 2];
                loadU<FPT / 8>(Hin + (long long)nc * K + f0, w);
#pragma unroll
                for (int i = 0; i < FPT / 2; ++i) {
                    float lo = bf16lo_f(w[i]), hi = bf16hi_f(w[i]);
                    a[2 * i] = BN ? fmaxf(fmaf(lo, sc[2 * i], sh[2 * i]), 0.f) : lo;
                    a[2 * i + 1] = BN ? fmaxf(fmaf(hi, sc[2 * i + 1], sh[2 * i + 1]), 0.f) : hi;
                }
            }
            for (int e = beg; e < end; ++e) {
                long long s = csr_src[e];
                unsigned w[FPT / 2];
                loadU<FPT / 8>(Hin + s * K + f0, w);
#pragma unroll
                for (int i = 0; i < FPT / 2; ++i) {
                    float lo = bf16lo_f(w[i]), hi = bf16hi_f(w[i]);
                    a[2 * i] += BN ? fmaxf(fmaf(lo, sc[2 * i], sh[2 * i]), 0.f) : lo;
                    a[2 * i + 1] += BN ? fmaxf(fmaf(hi, sc[2 * i + 1], sh[2 * i + 1]), 0.f) : hi;
                }
            }
#pragma unroll
            for (int c = 0; c < FPT / 8; ++c) {
                uint4 v;
                v.x = (unsigned)bf16_rne(a[c * 8 + 0]) | ((unsigned)bf16_rne(a[c * 8 + 1]) << 16);
                v.y = (unsigned)bf16_rne(a[c * 8 + 2]) | ((unsigned)bf16_rne(a[c * 8 + 3]) << 16);
                v.z = (unsigned)bf16_rne(a[c * 8 + 4]) | ((unsigned)bf16_rne(a[c * 8 + 5]) << 16);
                v.w = (unsigned)bf16_rne(a[c * 8 + 6]) | ((unsigned)bf16_rne(a[c * 8 + 7]) << 16);
                int col = f0 + c * 8;
                int bo = (nl * (K * 2) + col * 2) ^ ((nl & 7) << 4);
                *(uint4*)(lds_raw + bo) = v;
            }
        }
    }
    __syncthreads();

    floatx4 acc[4][4];
#pragma unroll
    for (int i = 0; i < 4; ++i)
#pragma unroll
        for (int j = 0; j < 4; ++j) acc[i][j] = (floatx4){0.f, 0.f, 0.f, 0.f};

    // ---------- stage 1: H = relu(A@W1+b1), A from LDS, W1 single-plane ----------
#pragma unroll
    for (int k0 = 0; k0 < K; k0 += 32) {
        short8v af[4], bh[4];
#pragma unroll
        for (int i = 0; i < 4; ++i) {
            int row = i * 16 + l15;
            int bo = (row * (K * 2) + (k0 + kgrp * 8) * 2) ^ ((row & 7) << 4);
            af[i] = *(const short8v*)(lds_raw + bo);
        }
#pragma unroll
        for (int j = 0; j < 4; ++j) {
            long long wb = (long long)(k0 >> 5) * 8192 + (wquarter + j) * 512 + laneoff;
            bh[j] = *(const short8v*)(W1 + wb);
        }
#pragma unroll
        for (int i = 0; i < 4; ++i)
#pragma unroll
            for (int j = 0; j < 4; ++j)
                acc[i][j] = __builtin_amdgcn_mfma_f32_16x16x32_bf16(af[i], bh[j], acc[i][j], 0, 0, 0);
    }
    __syncthreads();  // A fully consumed; safe to overwrite with H

    // write relu'd bf16 H tile into swizzled LDS [64][256]
#pragma unroll
    for (int j = 0; j < 4; ++j) {
        int col = wc * 64 + j * 16 + l15;
        float bb = b1[col];
#pragma unroll
        for (int i = 0; i < 4; ++i) {
            int lrow = i * 16 + rgrp;
#pragma unroll
            for (int r = 0; r < 4; ++r) {
                int row = lrow + r;
                float v = fmaxf(acc[i][j][r] + bb, 0.f);
                int bo = (row * 512 + col * 2) ^ ((row & 7) << 4);
                *(unsigned short*)(lds_raw + bo) = bf16_rne(v);
            }
        }
    }
    __syncthreads();

    // ---------- stage 2: out = H@W2+b2 (dual-plane W2) ----------
#pragma unroll
    for (int i = 0; i < 4; ++i)
#pragma unroll
        for (int j = 0; j < 4; ++j) acc[i][j] = (floatx4){0.f, 0.f, 0.f, 0.f};

#pragma unroll
    for (int k0 = 0; k0 < HID_C; k0 += 32) {
        short8v af[4], bh[4], bl[4];
#pragma unroll
        for (int i = 0; i < 4; ++i) {
            int row = i * 16 + l15;
            int bo = (row * 512 + (k0 + kgrp * 8) * 2) ^ ((row & 7) << 4);
            af[i] = *(const short8v*)(lds_raw + bo);
        }
#pragma unroll
        for (int j = 0; j < 4; ++j) {
            long long wb = (long long)(k0 >> 5) * 8192 + (wquarter + j) * 512 + laneoff;
            bh[j] = *(const short8v*)(W2h + wb);
            bl[j] = *(const short8v*)(W2l + wb);
        }
#pragma unroll
        for (int i = 0; i < 4; ++i)
#pragma unroll
            for (int j = 0; j < 4; ++j) {
                acc[i][j] = __builtin_amdgcn_mfma_f32_16x16x32_bf16(af[i], bh[j], acc[i][j], 0, 0, 0);
                acc[i][j] = __builtin_amdgcn_mfma_f32_16x16x32_bf16(af[i], bl[j], acc[i][j], 0, 0, 0);
            }
    }

    // fused BN column sums (exact fp32 from accumulators)
#pragma unroll
    for (int j = 0; j < 4; ++j) {
        int col = wc * 64 + j * 16 + l15;
        float bb = b2[col];
        float s1 = 0.f, s2 = 0.f;
#pragma unroll
        for (int i = 0; i < 4; ++i) {
            int rowb = gm + i * 16 + rgrp;
#pragma unroll
            for (int r = 0; r < 4; ++r) {
                if (rowb + r < M) {
                    float v = acc[i][j][r] + bb;
                    s1 += v; s2 += v * v;
                }
            }
        }
        s1 += __shfl_xor(s1, 16); s1 += __shfl_xor(s1, 32);
        s2 += __shfl_xor(s2, 16); s2 += __shfl_xor(s2, 32);
        if ((lane >> 4) == 0) {
            atomicAdd(&bnsums[col], s1);
            atomicAdd(&bnsums[HID_C + col], s2);
        }
    }

    // coalesced bf16 epilogue via LDS (reuse lds_raw), 2 col-half phases
    unsigned short* stg = (unsigned short*)lds_raw;  // [64][132]
#pragma unroll
    for (int p = 0; p < 2; ++p) {
        __syncthreads();
        if ((wc >> 1) == p) {
#pragma unroll
            for (int j = 0; j < 4; ++j) {
                int col = wc * 64 + j * 16 + l15;
                int lcol = (wc & 1) * 64 + j * 16 + l15;
                float bb = b2[col];
#pragma unroll
                for (int i = 0; i < 4; ++i) {
                    int lrow = i * 16 + rgrp;
#pragma unroll
                    for (int r = 0; r < 4; ++r)
                        stg[(lrow + r) * 132 + lcol] = bf16_rne(acc[i][j][r] + bb);
                }
            }
        }
        __syncthreads();
#pragma unroll
        for (int it = 0; it < 8; ++it) {
            int idx = it * 256 + tid;
            int row = idx >> 5;
            int c4 = idx & 31;
            int grow = gm + row;
            if (grow < M)
                *(ushort4*)(outH + (long long)grow * HID_C + p * 128 + c4 * 4) =
                    *(const ushort4*)&stg[row * 132 + c4 * 4];
        }
    }
}

// ---------------- BatchNorm finalize ----------------
__global__ void bn_finalize(const float* __restrict__ sums, const float* __restrict__ gamma,
                            const float* __restrict__ beta, float* __restrict__ ss) {
    int f = threadIdx.x;
    float mean = sums[f] * (1.0f / M_NODES);
    float var = sums[HID_C + f] * (1.0f / M_NODES) - mean * mean;
    float sc = gamma[f] * rsqrtf(var + BN_EPS_C);
    ss[f] = sc;
    ss[HID_C + f] = beta[f] - mean * sc;
}

// ---------------- pooling (bf16 in, fused BN+relu) ----------------
#define POOL_BLOCKS 4096
#define POOL_RPB 25
__global__ void pool_bn(const unsigned short* __restrict__ h, const float* __restrict__ ss,
                        const int* __restrict__ batch, float* __restrict__ sums, int M) {
    int f = threadIdx.x;
    float sc = ss[f], sh = ss[HID_C + f];
    int r0 = blockIdx.x * POOL_RPB;
    if (r0 >= M) return;
    int r1 = r0 + POOL_RPB;
    if (r1 > M) r1 = M;
    int cur = batch[r0];
    float acc = 0.f;
    for (int r = r0; r < r1; ++r) {
        int g = batch[r];
        if (g != cur) {
            atomicAdd(&sums[(long long)cur * HID_C + f], acc);
            acc = 0.f;
            cur = g;
        }
        float v = bf16_to_f(h[(long long)r * HID_C + f]);
        acc += fmaxf(fmaf(v, sc, sh), 0.f);
    }
    atomicAdd(&sums[(long long)cur * HID_C + f], acc);
}

__device__ __forceinline__ int lower_bound_i(const int* a, int n, int v) {
    int lo = 0, hi = n;
    while (lo < hi) {
        int mid = (lo + hi) >> 1;
        if (a[mid] < v) lo = mid + 1;
        else hi = mid;
    }
    return lo;
}

__global__ void pool_finalize(const float* __restrict__ sums, const int* __restrict__ batch,
                              float* __restrict__ out) {
    int g = blockIdx.x, f = threadIdx.x;
    int lb = lower_bound_i(batch, M_NODES, g);
    int ub = lower_bound_i(batch, M_NODES, g + 1);
    float cnt = (float)(ub - lb);
    out[(long long)g * HID_C + f] = sums[(long long)g * HID_C + f] / fmaxf(cnt, 1.0f);
}

// ---------------- launch ----------------
extern "C" void kernel_launch(void* const* d_in, const int* in_sizes, int n_in,
                              void* d_out, int out_size, void* d_ws, size_t ws_size,
                              hipStream_t stream) {
    const float* x = (const float*)d_in[0];
    const int* ei = (const int*)d_in[1];
    const int* esrc = ei;
    const int* edst = ei + N_EDGES_C;
    const int* batch = (const int*)d_in[2];
    const float* W1_0 = (const float*)d_in[3];
    const float* b1_0 = (const float*)d_in[4];
    const float* W2_0 = (const float*)d_in[5];
    const float* b2_0 = (const float*)d_in[6];
    const float* g0 = (const float*)d_in[7];
    const float* be0 = (const float*)d_in[8];
    const float* W1_1 = (const float*)d_in[9];
    const float* b1_1 = (const float*)d_in[10];
    const float* W2_1 = (const float*)d_in[11];
    const float* b2_1 = (const float*)d_in[12];
    const float* g1 = (const float*)d_in[13];
    const float* be1 = (const float*)d_in[14];
    float* out = (float*)d_out;

    const long long NF = (long long)M_NODES * HID_C;
    const long long NI = (long long)M_NODES * IN_DIM_C;
    unsigned short* U = (unsigned short*)d_ws;
    unsigned short* X16 = U;           // NI  (bf16 x)
    unsigned short* Hb0 = U + NI;      // NF  (pre-BN out L0)
    unsigned short* Hb1 = Hb0 + NF;    // NF  (pre-BN out L1)
    float* fbase = (float*)(Hb1 + NF);
    float* bns = fbase;
    float* ss0 = bns + 2 * HID_C;
    float* ss1 = ss0 + 2 * HID_C;
    float* psum = ss1 + 2 * HID_C;
    int* counts = (int*)(psum + N_GRAPHS_C * HID_C);
    int* partials = counts + 100352;
    int* rowptr = partials + 512;
    int* csr_src = rowptr + 100004;
    unsigned short* wp = (unsigned short*)(csr_src + N_EDGES_C);
    unsigned short* w1A = wp;                         // 128*256 single-plane
    unsigned short* wBh = w1A + IN_DIM_C * HID_C;     // 256*256 dual-plane
    unsigned short* wBl = wBh + HID_C * HID_C;
    unsigned short* w1C = wBl + HID_C * HID_C;        // 256*256 single-plane
    unsigned short* wDh = w1C + HID_C * HID_C;
    unsigned short* wDl = wDh + HID_C * HID_C;

    dim3 blk(256);
    dim3 fgrid((M_NODES + 63) / 64);

    // ---- W packs (fragment-major) ----
    wpack<IN_DIM_C><<<(IN_DIM_C * HID_C + 255) / 256, blk, 0, stream>>>(W1_0, w1A);
    wsplit<HID_C><<<(HID_C * HID_C + 255) / 256, blk, 0, stream>>>(W2_0, wBh, wBl);
    wpack<HID_C><<<(HID_C * HID_C + 255) / 256, blk, 0, stream>>>(W1_1, w1C);
    wsplit<HID_C><<<(HID_C * HID_C + 255) / 256, blk, 0, stream>>>(W2_1, wDh, wDl);

    // ---- CSR build ----
    zero_i<<<(M_NODES + 255) / 256, blk, 0, stream>>>(counts, M_NODES);
    csr_count<<<(N_EDGES_C + 255) / 256, blk, 0, stream>>>(edst, counts);
    block_scan<<<392, blk, 0, stream>>>(counts, rowptr, partials);
    scan_partials<<<1, 512, 0, stream>>>(partials, 392);
    add_offsets<<<392, blk, 0, stream>>>(rowptr, partials);
    copy_i<<<(M_NODES + 255) / 256, blk, 0, stream>>>(rowptr, counts, M_NODES);
    csr_fill<<<(N_EDGES_C + 255) / 256, blk, 0, stream>>>(esrc, edst, counts, csr_src);

    // ---- x -> bf16 ----
    f2b<<<(int)((NI / 4 + 255) / 256), blk, 0, stream>>>((const float4*)x, (ushort4*)X16,
                                                         (int)(NI / 4));

    // ---- Layer 0 (gather fused) ----
    zero_f<<<2, blk, 0, stream>>>(bns, 2 * HID_C);
    fused_gnn<IN_DIM_C, false><<<fgrid, blk, 0, stream>>>(X16, rowptr, csr_src, nullptr,
                                                          w1A, b1_0, wBh, wBl, b2_0,
                                                          Hb0, M_NODES, bns);
    bn_finalize<<<1, blk, 0, stream>>>(bns, g0, be0, ss0);

    // ---- Layer 1 (gather fused, prev-BN applied in gather) ----
    zero_f<<<2, blk, 0, stream>>>(bns, 2 * HID_C);
    fused_gnn<HID_C, true><<<fgrid, blk, 0, stream>>>(Hb0, rowptr, csr_src, ss0,
                                                      w1C, b1_1, wDh, wDl, b2_1,
                                                      Hb1, M_NODES, bns);
    bn_finalize<<<1, blk, 0, stream>>>(bns, g1, be1, ss1);

    // ---- Pool (fused BN+relu) ----
    zero_f<<<(N_GRAPHS_C * HID_C + 255) / 256, blk, 0, stream>>>(psum, N_GRAPHS_C * HID_C);
    pool_bn<<<POOL_BLOCKS, blk, 0, stream>>>(Hb1, ss1, batch, psum, M_NODES);
    pool_finalize<<<256, blk, 0, stream>>>(psum, batch, out);
}